// Round 6
// baseline (375.857 us; speedup 1.0000x reference)
//
#include <hip/hip_runtime.h>
#include <math.h>

// Problem constants (from reference): B=32, I=2048, O=32, C=16, U=32
#define B_   32
#define I_   2048
#define O_   32
#define C_   16
#define U_   32
#define NCOL   (O_ * U_)      // 1024 output columns (o,u)
#define TI     16             // i-values per block
#define NIG    (I_ / TI)      // 128 i-groups = partial slices
#define CQ     4              // column quarters -> grid = NIG*CQ = 512 blocks
#define SLICE  (B_ * NCOL)    // 32768 floats per partial slice
#define XS     36             // x LDS stride (floats): 144 B, mult of 16 -> aligned b128
#define CHUNKS (TI * 2)       // 32 pipeline chunks (8 c-values each)

// softmax over the singleton axis of b_log is identically 1 -> routing
// iterations are no-ops. Output = squash(sum_{i,c} x[b,i,c] * w[i,o,c,u]).
//
// R6: R5 was latency-bound (VGPR_Count=36 -> compiler kept ~2 loads in
// flight; 1.2 TB/s, VALUBusy 18%). Explicit 2-stage software pipeline:
// wv[2][8], prefetch chunk k+1 while computing chunk k -> 8 b128 loads
// in flight per thread, issued a full compute-stage early. TI=16 halves
// partial traffic (16 MB); grid 512 = 2 blocks/CU = 16 waves/CU.

__global__ __launch_bounds__(512, 4) void caps_partial(const float* __restrict__ x,
                                                       const float* __restrict__ w,
                                                       float* __restrict__ ws) {
    __shared__ float xs[TI * C_ * XS];   // 9216 floats = 36 KB; xs[rem*36 + b]
    const int tid = threadIdx.x;         // 0..511
    const int ig  = blockIdx.x >> 2;     // i-group
    const int cq  = blockIdx.x & 3;      // column quarter
    const int i0  = ig * TI;

    // Stage x[:, i0:i0+TI, :] -> LDS. Global coalesced (256 consecutive
    // floats per b). 16 scalar LDS writes/thread, once (conflicts negligible).
    for (int k = tid; k < B_ * TI * C_; k += 512) {
        int b   = k >> 8;                // / (TI*C_) == 256
        int rem = k & 255;
        xs[rem * XS + b] = x[(size_t)b * (I_ * C_) + (size_t)i0 * C_ + rem];
    }
    __syncthreads();

    const int colf4 = tid & 63;          // f4-column within quarter
    const int bg    = tid >> 6;          // batch group (4 batches), wave-uniform
    const int o     = cq * 8 + (colf4 >> 3);
    const int u4    = (colf4 & 7) << 2;
    const float* wp = w + (size_t)i0 * (O_ * C_ * U_) + o * (C_ * U_) + u4;
    const float* xb = xs + bg * 4;

    float4 acc[4];
#pragma unroll
    for (int b = 0; b < 4; ++b) acc[b] = make_float4(0.f, 0.f, 0.f, 0.f);

    float4 wv[2][8];
    // Prologue: chunk 0 (il=0, cc=0).
#pragma unroll
    for (int j = 0; j < 8; ++j)
        wv[0][j] = *(const float4*)(wp + j * U_);

#pragma unroll 2
    for (int k = 0; k < CHUNKS; ++k) {
        const int cur = k & 1;
        const int nxt = cur ^ 1;
        // Prefetch chunk k+1: 8 independent b128 loads, a full compute
        // stage ahead of their use (cross-iteration dependence forces
        // the compiler to keep them in flight).
        if (k + 1 < CHUNKS) {
            const int il1 = (k + 1) >> 1;
            const int cc1 = ((k + 1) & 1) * 8;
            const float* wpn = wp + (size_t)il1 * (O_ * C_ * U_) + cc1 * U_;
#pragma unroll
            for (int j = 0; j < 8; ++j)
                wv[nxt][j] = *(const float4*)(wpn + j * U_);
        }
        // Compute chunk k (x from LDS: wave-uniform broadcast b128 reads).
        const int il = k >> 1;
        const int cc = (k & 1) * 8;
        const float* xr = xb + (il * C_ + cc) * XS;
#pragma unroll
        for (int j = 0; j < 8; ++j) {
            float4 xq = *(const float4*)(xr + j * XS);
            float4 wj = wv[cur][j];
            acc[0].x = fmaf(xq.x, wj.x, acc[0].x);
            acc[0].y = fmaf(xq.x, wj.y, acc[0].y);
            acc[0].z = fmaf(xq.x, wj.z, acc[0].z);
            acc[0].w = fmaf(xq.x, wj.w, acc[0].w);
            acc[1].x = fmaf(xq.y, wj.x, acc[1].x);
            acc[1].y = fmaf(xq.y, wj.y, acc[1].y);
            acc[1].z = fmaf(xq.y, wj.z, acc[1].z);
            acc[1].w = fmaf(xq.y, wj.w, acc[1].w);
            acc[2].x = fmaf(xq.z, wj.x, acc[2].x);
            acc[2].y = fmaf(xq.z, wj.y, acc[2].y);
            acc[2].z = fmaf(xq.z, wj.z, acc[2].z);
            acc[2].w = fmaf(xq.z, wj.w, acc[2].w);
            acc[3].x = fmaf(xq.w, wj.x, acc[3].x);
            acc[3].y = fmaf(xq.w, wj.y, acc[3].y);
            acc[3].z = fmaf(xq.w, wj.z, acc[3].z);
            acc[3].w = fmaf(xq.w, wj.w, acc[3].w);
        }
    }

    // ws[ig][b][col], col = cq*256 + colf4*4. Coalesced float4 stores
    // (64 lanes x 16 B = 1 KB contiguous per store instruction).
    float* op = ws + (size_t)ig * SLICE + (size_t)(bg * 4) * NCOL + cq * 256 + colf4 * 4;
#pragma unroll
    for (int b = 0; b < 4; ++b)
        *(float4*)(op + (size_t)b * NCOL) = acc[b];
}

// Sum 128 partials per output element (4 threads/element over p-quarters),
// then squash over u (32 consecutive t = one (b,o) group; shuffle reduce).
__global__ __launch_bounds__(256) void caps_reduce_squash(const float* __restrict__ ws,
                                                          float* __restrict__ out) {
    __shared__ float sh[256];
    const int tid = threadIdx.x;
    const int tl = tid & 63;
    const int ph = tid >> 6;                   // p-quarter 0..3 (one wave each)
    const int t  = blockIdx.x * 64 + tl;       // t in [0, 32768)
    const float* p = ws + (size_t)ph * (NIG / 4) * SLICE + t;
    float s = 0.f;
#pragma unroll 8
    for (int i = 0; i < NIG / 4; ++i)          // 32 independent strided loads
        s += p[(size_t)i * SLICE];
    sh[tid] = s;
    __syncthreads();
    if (ph == 0) {
        s = sh[tl] + sh[64 + tl] + sh[128 + tl] + sh[192 + tl];
        float ss = s * s;
        ss += __shfl_xor(ss, 1);
        ss += __shfl_xor(ss, 2);
        ss += __shfl_xor(ss, 4);
        ss += __shfl_xor(ss, 8);
        ss += __shfl_xor(ss, 16);
        float n = sqrtf(ss);
        out[t] = s * n / (1.0f + ss);
    }
}

// ---------------- fallback (atomic path) if ws too small ----------------
__global__ __launch_bounds__(256, 2) void caps_main_atomic(const float* __restrict__ x,
                                                           const float* __restrict__ w,
                                                           float* __restrict__ out) {
    __shared__ float xsf[4 * C_ * 33];
    const int tid = threadIdx.x;
    const int i0 = blockIdx.x * 4;
    for (int k = tid; k < B_ * 4 * C_; k += 256) {
        int b = k >> 6, rem = k & 63;
        xsf[rem * 33 + b] = x[(size_t)b * (I_ * C_) + (size_t)i0 * C_ + rem];
    }
    __syncthreads();
    const int o = tid >> 3, u4 = (tid & 7) << 2;
    const float* wp = w + (size_t)i0 * (O_ * C_ * U_) + o * (C_ * U_) + u4;
    float4 acc[B_];
#pragma unroll
    for (int b = 0; b < B_; ++b) acc[b] = make_float4(0.f, 0.f, 0.f, 0.f);
    for (int il = 0; il < 4; ++il) {
        const float* wpi = wp + (size_t)il * (O_ * C_ * U_);
        const float* xr = &xsf[il * C_ * 33];
#pragma unroll
        for (int c = 0; c < C_; ++c) {
            float4 wv = *(const float4*)(wpi + c * U_);
            const float* xc = xr + c * 33;
#pragma unroll
            for (int b = 0; b < B_; ++b) {
                float xb = xc[b];
                acc[b].x = fmaf(xb, wv.x, acc[b].x);
                acc[b].y = fmaf(xb, wv.y, acc[b].y);
                acc[b].z = fmaf(xb, wv.z, acc[b].z);
                acc[b].w = fmaf(xb, wv.w, acc[b].w);
            }
        }
    }
    float* op = out + o * U_ + u4;
#pragma unroll
    for (int b = 0; b < B_; ++b) {
        float* p = op + (size_t)b * NCOL;
        atomicAdd(p + 0, acc[b].x);
        atomicAdd(p + 1, acc[b].y);
        atomicAdd(p + 2, acc[b].z);
        atomicAdd(p + 3, acc[b].w);
    }
}

__global__ void caps_squash_inplace(float* __restrict__ out) {
    int t = blockIdx.x * 256 + threadIdx.x;
    float s = out[t];
    float ss = s * s;
    ss += __shfl_xor(ss, 1);
    ss += __shfl_xor(ss, 2);
    ss += __shfl_xor(ss, 4);
    ss += __shfl_xor(ss, 8);
    ss += __shfl_xor(ss, 16);
    float n = sqrtf(ss);
    out[t] = s * n / (1.0f + ss);
}

extern "C" void kernel_launch(void* const* d_in, const int* in_sizes, int n_in,
                              void* d_out, int out_size, void* d_ws, size_t ws_size,
                              hipStream_t stream) {
    const float* x = (const float*)d_in[0];   // [B, I, C]
    const float* w = (const float*)d_in[1];   // [I, O, C, U]
    float* out = (float*)d_out;               // [B, O, 1, U] = 32768 floats

    const size_t need = (size_t)NIG * SLICE * sizeof(float);   // 16 MB
    if (ws_size >= need) {
        float* ws = (float*)d_ws;
        caps_partial<<<NIG * CQ, 512, 0, stream>>>(x, w, ws);
        caps_reduce_squash<<<SLICE / 64, 256, 0, stream>>>(ws, out);
    } else {
        hipMemsetAsync(out, 0, (size_t)SLICE * sizeof(float), stream);
        caps_main_atomic<<<I_ / 4, 256, 0, stream>>>(x, w, out);
        caps_squash_inplace<<<SLICE / 256, 256, 0, stream>>>(out);
    }
}

// Round 7
// 223.328 us; speedup vs baseline: 1.6830x; 1.6830x over previous
//
#include <hip/hip_runtime.h>
#include <math.h>

// Problem constants (from reference): B=32, I=2048, O=32, C=16, U=32
#define B_   32
#define I_   2048
#define O_   32
#define C_   16
#define U_   32
#define NCOL   (O_ * U_)      // 1024 output columns (o,u)
#define TI     8              // i-values per block
#define NIG    (I_ / TI)      // 256 i-groups = partial slices
#define CQ     4              // column quarters -> grid = NIG*CQ = 1024 blocks
#define SLICE  (B_ * NCOL)    // 32768 floats per partial slice
#define XS     36             // x LDS stride (floats): 144 B, mult of 16 -> aligned b128
#define WTILE  (8 * C_ * U_)  // 4096 floats = 16 KB: one il's w-tile for this cq

// softmax over the singleton axis of b_log is identically 1 -> routing
// iterations are no-ops. Output = squash(sum_{i,c} x[b,i,c] * w[i,o,c,u]).
//
// R7: registers as prefetch buffers failed twice (R4/R6: scratch spill;
// R5: compiler collapsed loads next-to-use -> latency-bound 1.2 TB/s).
// m97 structure instead: double-buffered LDS w-tiles. Per il: issue 4
// coalesced float4 global loads (tile il+1) into NAMED regs at loop top;
// compute il from LDS; ds_write regs -> other buffer at loop bottom
// (vmcnt wait lands there, AFTER the ~1200cy compute phase); barrier.
// 4 KB in flight per wave through compute + 3 blocks/CU staggered keeps
// HBM busy. 256 thr, 8 batches/thread (acc[8]f4=32 VGPR), LDS 50.4 KB.

__global__ __launch_bounds__(256, 3) void caps_partial(const float* __restrict__ x,
                                                       const float* __restrict__ w,
                                                       float* __restrict__ ws) {
    __shared__ float wbuf[2][WTILE];     // 32 KB double-buffered w tile
    __shared__ float xs[TI * C_ * XS];   // 18.4 KB; xs[rem*36 + b]
    const int tid = threadIdx.x;         // 0..255
    const int ig  = blockIdx.x >> 2;     // i-group
    const int cq  = blockIdx.x & 3;      // column quarter (8 o's)
    const int i0  = ig * TI;

    // Stage x[:, i0:i0+TI, :] -> LDS. Global coalesced (128 consecutive
    // floats per b). One-time; staging-write bank conflicts negligible.
    for (int k = tid; k < B_ * TI * C_; k += 256) {
        int b   = k >> 7;                // / (TI*C_) == 128
        int rem = k & 127;
        xs[rem * XS + b] = x[(size_t)b * (I_ * C_) + (size_t)i0 * C_ + rem];
    }

    // w tile for il: 16 KB contiguous at w + ((i0+il)*O + cq*8)*(C*U).
    const float4* wt0 = (const float4*)(w + ((size_t)i0 * O_ + (size_t)cq * 8) * (C_ * U_));
    const int tstride = O_ * C_ * U_ / 4;   // f4 stride between consecutive i

    // Prologue: stage tile 0 (4 coalesced float4 loads -> LDS).
    float4 p0 = wt0[tid];
    float4 p1 = wt0[tid + 256];
    float4 p2 = wt0[tid + 512];
    float4 p3 = wt0[tid + 768];
    {
        float4* wd = (float4*)wbuf[0];
        wd[tid]       = p0;
        wd[tid + 256] = p1;
        wd[tid + 512] = p2;
        wd[tid + 768] = p3;
    }
    __syncthreads();

    const int colf4 = tid & 63;          // f4-column within quarter (lane id)
    const int bg    = tid >> 6;          // batch group (8 batches), wave-uniform
    const int ol    = colf4 >> 3;        // local o 0..7
    const int u4    = (colf4 & 7) << 2;
    const float* xbase = xs + bg * 8;    // batches bg*8 .. bg*8+7

    float4 acc[8];
#pragma unroll
    for (int b = 0; b < 8; ++b) acc[b] = make_float4(0.f, 0.f, 0.f, 0.f);

    for (int il = 0; il < TI; ++il) {
        const int cur = il & 1;
        // Issue next tile's 4 global loads now; they stay in flight through
        // the compute phase (vmcnt wait sits before the ds_writes below).
        float4 q0, q1, q2, q3;
        if (il + 1 < TI) {
            const float4* wn = wt0 + (size_t)(il + 1) * tstride;
            q0 = wn[tid];
            q1 = wn[tid + 256];
            q2 = wn[tid + 512];
            q3 = wn[tid + 768];
        }
        // Compute tile il from LDS. w reads: ds_read_b128, all 32 banks
        // covered evenly (bandwidth-optimal). x reads: wave-uniform b128
        // broadcasts (conflict-free).
        const float* wrow = &wbuf[cur][ol * (C_ * U_) + u4];
        const float* xrow = xbase + il * C_ * XS;
#pragma unroll
        for (int c = 0; c < C_; ++c) {
            float4 wv = *(const float4*)(wrow + c * U_);
            float4 xa = *(const float4*)(xrow + c * XS);       // batches +0..3
            float4 xb = *(const float4*)(xrow + c * XS + 4);   // batches +4..7
            acc[0].x = fmaf(xa.x, wv.x, acc[0].x);
            acc[0].y = fmaf(xa.x, wv.y, acc[0].y);
            acc[0].z = fmaf(xa.x, wv.z, acc[0].z);
            acc[0].w = fmaf(xa.x, wv.w, acc[0].w);
            acc[1].x = fmaf(xa.y, wv.x, acc[1].x);
            acc[1].y = fmaf(xa.y, wv.y, acc[1].y);
            acc[1].z = fmaf(xa.y, wv.z, acc[1].z);
            acc[1].w = fmaf(xa.y, wv.w, acc[1].w);
            acc[2].x = fmaf(xa.z, wv.x, acc[2].x);
            acc[2].y = fmaf(xa.z, wv.y, acc[2].y);
            acc[2].z = fmaf(xa.z, wv.z, acc[2].z);
            acc[2].w = fmaf(xa.z, wv.w, acc[2].w);
            acc[3].x = fmaf(xa.w, wv.x, acc[3].x);
            acc[3].y = fmaf(xa.w, wv.y, acc[3].y);
            acc[3].z = fmaf(xa.w, wv.z, acc[3].z);
            acc[3].w = fmaf(xa.w, wv.w, acc[3].w);
            acc[4].x = fmaf(xb.x, wv.x, acc[4].x);
            acc[4].y = fmaf(xb.x, wv.y, acc[4].y);
            acc[4].z = fmaf(xb.x, wv.z, acc[4].z);
            acc[4].w = fmaf(xb.x, wv.w, acc[4].w);
            acc[5].x = fmaf(xb.y, wv.x, acc[5].x);
            acc[5].y = fmaf(xb.y, wv.y, acc[5].y);
            acc[5].z = fmaf(xb.y, wv.z, acc[5].z);
            acc[5].w = fmaf(xb.y, wv.w, acc[5].w);
            acc[6].x = fmaf(xb.z, wv.x, acc[6].x);
            acc[6].y = fmaf(xb.z, wv.y, acc[6].y);
            acc[6].z = fmaf(xb.z, wv.z, acc[6].z);
            acc[6].w = fmaf(xb.z, wv.w, acc[6].w);
            acc[7].x = fmaf(xb.w, wv.x, acc[7].x);
            acc[7].y = fmaf(xb.w, wv.y, acc[7].y);
            acc[7].z = fmaf(xb.w, wv.z, acc[7].z);
            acc[7].w = fmaf(xb.w, wv.w, acc[7].w);
        }
        // Drain the prefetch into the other buffer (waitcnt lands here).
        if (il + 1 < TI) {
            float4* wd = (float4*)wbuf[cur ^ 1];
            wd[tid]       = q0;
            wd[tid + 256] = q1;
            wd[tid + 512] = q2;
            wd[tid + 768] = q3;
        }
        __syncthreads();
    }

    // ws[ig][b][col], col = cq*256 + colf4*4. Coalesced float4 stores.
    float* op = ws + (size_t)ig * SLICE + (size_t)(bg * 8) * NCOL + cq * 256 + colf4 * 4;
#pragma unroll
    for (int b = 0; b < 8; ++b)
        *(float4*)(op + (size_t)b * NCOL) = acc[b];
}

// Sum 256 partials per output element (4 threads/element over p-quarters),
// then squash over u (32 consecutive t = one (b,o) group; shuffle reduce).
__global__ __launch_bounds__(256) void caps_reduce_squash(const float* __restrict__ ws,
                                                          float* __restrict__ out) {
    __shared__ float sh[256];
    const int tid = threadIdx.x;
    const int tl = tid & 63;
    const int ph = tid >> 6;                   // p-quarter 0..3 (one wave each)
    const int t  = blockIdx.x * 64 + tl;       // t in [0, 32768)
    const float* p = ws + (size_t)ph * (NIG / 4) * SLICE + t;
    float s = 0.f;
#pragma unroll 8
    for (int i = 0; i < NIG / 4; ++i)          // 64 independent strided loads
        s += p[(size_t)i * SLICE];
    sh[tid] = s;
    __syncthreads();
    if (ph == 0) {
        s = sh[tl] + sh[64 + tl] + sh[128 + tl] + sh[192 + tl];
        float ss = s * s;
        ss += __shfl_xor(ss, 1);
        ss += __shfl_xor(ss, 2);
        ss += __shfl_xor(ss, 4);
        ss += __shfl_xor(ss, 8);
        ss += __shfl_xor(ss, 16);
        float n = sqrtf(ss);
        out[t] = s * n / (1.0f + ss);
    }
}

// ---------------- fallback (atomic path) if ws too small ----------------
__global__ __launch_bounds__(256, 2) void caps_main_atomic(const float* __restrict__ x,
                                                           const float* __restrict__ w,
                                                           float* __restrict__ out) {
    __shared__ float xsf[4 * C_ * 33];
    const int tid = threadIdx.x;
    const int i0 = blockIdx.x * 4;
    for (int k = tid; k < B_ * 4 * C_; k += 256) {
        int b = k >> 6, rem = k & 63;
        xsf[rem * 33 + b] = x[(size_t)b * (I_ * C_) + (size_t)i0 * C_ + rem];
    }
    __syncthreads();
    const int o = tid >> 3, u4 = (tid & 7) << 2;
    const float* wp = w + (size_t)i0 * (O_ * C_ * U_) + o * (C_ * U_) + u4;
    float4 acc[B_];
#pragma unroll
    for (int b = 0; b < B_; ++b) acc[b] = make_float4(0.f, 0.f, 0.f, 0.f);
    for (int il = 0; il < 4; ++il) {
        const float* wpi = wp + (size_t)il * (O_ * C_ * U_);
        const float* xr = &xsf[il * C_ * 33];
#pragma unroll
        for (int c = 0; c < C_; ++c) {
            float4 wv = *(const float4*)(wpi + c * U_);
            const float* xc = xr + c * 33;
#pragma unroll
            for (int b = 0; b < B_; ++b) {
                float xb = xc[b];
                acc[b].x = fmaf(xb, wv.x, acc[b].x);
                acc[b].y = fmaf(xb, wv.y, acc[b].y);
                acc[b].z = fmaf(xb, wv.z, acc[b].z);
                acc[b].w = fmaf(xb, wv.w, acc[b].w);
            }
        }
    }
    float* op = out + o * U_ + u4;
#pragma unroll
    for (int b = 0; b < B_; ++b) {
        float* p = op + (size_t)b * NCOL;
        atomicAdd(p + 0, acc[b].x);
        atomicAdd(p + 1, acc[b].y);
        atomicAdd(p + 2, acc[b].z);
        atomicAdd(p + 3, acc[b].w);
    }
}

__global__ void caps_squash_inplace(float* __restrict__ out) {
    int t = blockIdx.x * 256 + threadIdx.x;
    float s = out[t];
    float ss = s * s;
    ss += __shfl_xor(ss, 1);
    ss += __shfl_xor(ss, 2);
    ss += __shfl_xor(ss, 4);
    ss += __shfl_xor(ss, 8);
    ss += __shfl_xor(ss, 16);
    float n = sqrtf(ss);
    out[t] = s * n / (1.0f + ss);
}

extern "C" void kernel_launch(void* const* d_in, const int* in_sizes, int n_in,
                              void* d_out, int out_size, void* d_ws, size_t ws_size,
                              hipStream_t stream) {
    const float* x = (const float*)d_in[0];   // [B, I, C]
    const float* w = (const float*)d_in[1];   // [I, O, C, U]
    float* out = (float*)d_out;               // [B, O, 1, U] = 32768 floats

    const size_t need = (size_t)NIG * SLICE * sizeof(float);   // 32 MB
    if (ws_size >= need) {
        float* ws = (float*)d_ws;
        caps_partial<<<NIG * CQ, 256, 0, stream>>>(x, w, ws);
        caps_reduce_squash<<<SLICE / 64, 256, 0, stream>>>(ws, out);
    } else {
        hipMemsetAsync(out, 0, (size_t)SLICE * sizeof(float), stream);
        caps_main_atomic<<<I_ / 4, 256, 0, stream>>>(x, w, out);
        caps_squash_inplace<<<SLICE / 256, 256, 0, stream>>>(out);
    }
}